// Round 14
// baseline (845.980 us; speedup 1.0000x reference)
//
#include <hip/hip_runtime.h>

typedef unsigned short u16;
typedef u16 u16x8 __attribute__((ext_vector_type(8)));
typedef __bf16 bf16x8 __attribute__((ext_vector_type(8)));
typedef float f32x4 __attribute__((ext_vector_type(4)));

#define DEV __device__ __forceinline__
#define MFMA16 __builtin_amdgcn_mfma_f32_16x16x32_bf16

constexpr int Bb = 2, Nctx = 2048, Dm = 512, Hh = 8, Dh = 512, Ff = 4096;
constexpr int Mrows = Bb * Nctx;  // 4096

DEV float b2f(u16 u) { unsigned int i = ((unsigned int)u) << 16; return __builtin_bit_cast(float, i); }
DEV u16 f2b(float f) {
  unsigned int x = __builtin_bit_cast(unsigned int, f);
  return (u16)((x + 0x7FFFu + ((x >> 16) & 1u)) >> 16);
}
DEV bf16x8 ld8(const u16* p) { return __builtin_bit_cast(bf16x8, *(const u16x8*)p); }

// async global->LDS, 16B per lane. LDS dest must be wave-uniform base + lane*16.
DEV void gload16(const u16* g, u16* l) {
#if defined(__has_builtin) && __has_builtin(__builtin_amdgcn_global_load_lds)
  __builtin_amdgcn_global_load_lds((const __attribute__((address_space(1))) void*)(g),
                                   (__attribute__((address_space(3))) void*)(l), 16, 0, 0);
#else
  *(u16x8*)l = *(const u16x8*)g;
#endif
}

// ---------------- f32 -> bf16 convert ----------------
__global__ void convert_k(const float* __restrict__ in, u16* __restrict__ out, int n8) {
  int idx = blockIdx.x * 256 + threadIdx.x;
  if (idx >= n8) return;
  size_t e0 = (size_t)idx * 8;
  f32x4 a = *(const f32x4*)(in + e0);
  f32x4 b = *(const f32x4*)(in + e0 + 4);
  u16x8 o;
  #pragma unroll
  for (int i = 0; i < 4; ++i) { o[i] = f2b(a[i]); o[4 + i] = f2b(b[i]); }
  *(u16x8*)(out + e0) = o;
}

// ---------------- transpose + convert: out_bf16[c][r] = in_f32[r][c] ----------------
__global__ void transpose_k(const float* __restrict__ in, u16* __restrict__ out,
                            int rows, int cols) {
  __shared__ float tile[32][33];
  int bx = blockIdx.x * 32, by = blockIdx.y * 32;
  int tx = threadIdx.x, ty = threadIdx.y;
  #pragma unroll
  for (int i = ty; i < 32; i += 8)
    tile[i][tx] = in[(size_t)(by + i) * cols + bx + tx];
  __syncthreads();
  #pragma unroll
  for (int i = ty; i < 32; i += 8)
    out[(size_t)(bx + i) * rows + by + tx] = f2b(tile[tx][i]);
}

// ---- batched V transpose v2: Vt[bh][d][n] = V[b*N+n][h*Dh+d], 16B both sides ----
// Verified rounds 7-13.
__global__ void vtrans_k(const u16* __restrict__ V, u16* __restrict__ Vt) {
  __shared__ u16 tile[64 * 64];
  const int z = blockIdx.z;  // b*8+h
  const int b = z >> 3, h = z & 7;
  const int n0 = blockIdx.x * 64, d0 = blockIdx.y * 64;
  const int t = threadIdx.x;  // 0..255
  const int nl = t >> 3;      // 0..31
  const int dg = t & 7;       // 8-wide group
  #pragma unroll
  for (int sw = 0; sw < 2; ++sw) {
    int n = nl + 32 * sw;
    u16x8 v = *(const u16x8*)&V[((size_t)(b * Nctx + n0 + n)) * Ff + h * Dh + d0 + dg * 8];
    #pragma unroll
    for (int j = 0; j < 8; ++j) {
      int d = dg * 8 + j;
      int g = ((d & 7) ^ (d >> 3)) & 7;
      tile[d * 64 + (n ^ (g << 3))] = v[j];
    }
  }
  __syncthreads();
  #pragma unroll
  for (int sw = 0; sw < 2; ++sw) {
    int d = nl + 32 * sw;
    int g = ((d & 7) ^ (d >> 3)) & 7;
    u16x8 v = *(const u16x8*)&tile[d * 64 + ((dg ^ g) << 3)];
    *(u16x8*)&Vt[((size_t)(z * Dh + d0 + d)) * Nctx + n0 + dg * 8] = v;
  }
}

// ------- GEMM 128x128 tile, BK=64, global_load_lds staging, 4 waves 2x2 -------
// Verified rounds 7-13. SEPARATE launches per Q/K/V (round 9: merged -31us).
// MODE: 0 plain->bf16, 1 rope->bf16, 2 bias->bf16, 3 bias->f32
template <int MODE>
__launch_bounds__(256, 4)
__global__ void gemm2_k(const u16* __restrict__ A, const u16* __restrict__ BT,
                        void* __restrict__ Cout, const float* __restrict__ bias,
                        const float* __restrict__ cs, const float* __restrict__ sn,
                        int Ndim, int Kdim) {
  __shared__ u16 sA[128 * 64];
  __shared__ u16 sB[128 * 64];
  const int tid = threadIdx.x;
  const int wave = tid >> 6, lane = tid & 63, quad = lane >> 4, l16 = lane & 15;
  const int wy = wave >> 1, wx = wave & 1;
  const int m0 = blockIdx.y * 128, n0 = blockIdx.x * 128;
  f32x4 acc[4][4];
  #pragma unroll
  for (int i = 0; i < 4; ++i)
    #pragma unroll
    for (int j = 0; j < 4; ++j)
      #pragma unroll
      for (int r = 0; r < 4; ++r) acc[i][j][r] = 0.f;
  const int srow = tid >> 3;        // 0..31 (32 rows per staging sweep)
  const int scol = (tid & 7) * 8;   // 0..56; LDS dest = tid*16B (wave-linear)
  for (int k0 = 0; k0 < Kdim; k0 += 64) {
    __syncthreads();
    #pragma unroll
    for (int sw = 0; sw < 4; ++sw) {
      int row = srow + 32 * sw;
      int sc = scol ^ ((row & 7) * 8);  // pre-swizzled source column
      gload16(A + (size_t)(m0 + row) * Kdim + k0 + sc, &sA[row * 64 + scol]);
      gload16(BT + (size_t)(n0 + row) * Kdim + k0 + sc, &sB[row * 64 + scol]);
    }
    __syncthreads();
    #pragma unroll
    for (int kk2 = 0; kk2 < 2; ++kk2) {
      const int cbase = (kk2 * 32 + quad * 8) ^ ((l16 & 7) * 8);
      bf16x8 af[4], bf[4];
      #pragma unroll
      for (int t = 0; t < 4; ++t) af[t] = ld8(&sA[(wy * 64 + t * 16 + l16) * 64 + cbase]);
      #pragma unroll
      for (int t = 0; t < 4; ++t) bf[t] = ld8(&sB[(wx * 64 + t * 16 + l16) * 64 + cbase]);
      #pragma unroll
      for (int i = 0; i < 4; ++i)
        #pragma unroll
        for (int j = 0; j < 4; ++j)
          acc[i][j] = MFMA16(af[i], bf[j], acc[i][j], 0, 0, 0);
    }
  }
  #pragma unroll
  for (int i = 0; i < 4; ++i) {
    #pragma unroll
    for (int j = 0; j < 4; ++j) {
      int col = n0 + wx * 64 + j * 16 + l16;
      float badd = (MODE == 2 || MODE == 3) ? bias[col] : 0.f;
      #pragma unroll
      for (int r = 0; r < 4; ++r) {
        int row = m0 + wy * 64 + i * 16 + quad * 4 + r;  // C: col=lane&15, row=quad*4+reg
        float v = acc[i][j][r] + badd;
        if (MODE == 1) {  // fused RoPE: pairs (col even, col odd) across lane^1
          float vp = __shfl_xor(v, 1);
          int n = row & (Nctx - 1);
          float c = cs[(size_t)n * Ff + col];
          float s = sn[(size_t)n * Ff + col];
          v = (l16 & 1) ? (v * c + vp * s) : (v * c - vp * s);
        }
        if (MODE == 3) ((float*)Cout)[(size_t)row * Ndim + col] = v;
        else           ((u16*)Cout)[(size_t)row * Ndim + col] = f2b(v);
      }
    }
  }
}

// ------- flash attention v5: wave-specialized pipeline at QBLK=32/KVBLK=32 -------
// 512 blocks x 512 thr (8 waves), 2 blocks/CU = 16 waves/CU (4/SIMD).
// Rounds 3-5 proved the 8-wave pipeline CORRECT but spilled: 8-wave blocks are
// allocator-pinned to 128 VGPR and QBLK=64 needed acc128+qf64=192. Fix: shrink
// so both roles fit 128: PV waves acc[2][8]=64 (32 rows x 128-dh slice); QK
// waves stream Q fragments from the L2-resident 32KB Q tile (#pragma unroll 4
// window ~16 regs) instead of a 64-reg qf array. Union ~115 <= 128.
// Roles: waves 0-3 (A): QK^T, split (rowg=w>>1, keyg=w&1) 16 rows x 16 keys
// each -> raw f32 scores to sS pre-MID; post-MID waves 0-1 do full-row online
// softmax (16 rows x 32 keys each) -> sP[pg]/sAl[pg] ping-pong. Waves 4-7 (B):
// pre-MID PV(tile s-1) from sP[(s-1)&1] + V direct from L2 (round-6 pattern,
// wave-private 128-dh slice); post-MID stageK(s+1) DMA (in flight past TOP).
// MID = raw s_barrier + lgkmcnt(0) only (round-3/4-verified ordering).
// Schedule: paired phases qt = p / 63-p (65 tiles constant, round-2-proven),
// phase-1 jt descending; XCD-affine decode (idx&7 = h). LDS ~43KB.
// NO setprio (round 7). Diag tile = jt==qt only (32-aligned tiles).
__launch_bounds__(512, 1)
__global__ void attn_k(const u16* __restrict__ Q, const u16* __restrict__ K,
                       const u16* __restrict__ Vt, u16* __restrict__ Yp) {
  __shared__ u16 sK[32 * 512];     // [key][dh], phys chunk16 = (chunk+key)&63
  __shared__ float sS[32 * 36];    // raw QK^T scores (f32), A-group exchange
  __shared__ u16 sP[2][32 * 40];   // ping-pong P tiles (bf16)
  __shared__ float sAl[2][32];     // ping-pong alpha
  __shared__ float sL[32];
  const int idx = blockIdx.x;
  const int hi = (idx >> 8) & 1;
  const int bh = (idx & 7) | (hi << 3);  // XCD-affine: idx%8 pins h per XCD
  const int p = (idx >> 3) & 31;         // pair index: qt = p then 63-p
  const int b = bh >> 3, h = bh & 7;
  const int wave = threadIdx.x >> 6, lane = threadIdx.x & 63;
  const int quad = lane >> 4, l16 = lane & 15;
  const bool isA = (wave < 4);
  const int rowg = (wave >> 1) & 1;  // A: QK row group (16 rows)
  const int keyg = wave & 1;         // A: QK key group (16 keys)
  const int wb = wave & 3;           // B: role-local wave id
  const int wd = wb * 128;           // B: PV dh-slice

  auto stageK = [&](int j0) {  // B group: 32 rows, 8 per wave
    #pragma unroll
    for (int it = 0; it < 8; ++it) {
      int row = wb * 8 + it;
      const u16* gp = K + ((size_t)(b * Nctx + j0 + row)) * Ff + h * Dh + (((lane - row) & 63) * 8);
      gload16(gp, &sK[row * 512 + lane * 8]);
    }
  };
  const u16* vrow = Vt + ((size_t)(bh * Dh + wd + l16)) * Nctx;

  for (int phase = 0; phase < 2; ++phase) {
    const int qt = phase ? (63 - p) : p;   // 0..63
    const bool asc = (phase == 0);
    const int q0 = qt * 32;
    const int NT = qt + 1;

    f32x4 acc[2][8];
    float mrun[4], lrun[4];
    const u16* qp = Q + ((size_t)(b * Nctx + q0 + rowg * 16 + l16)) * Ff + h * Dh + quad * 8;
    if (isA) {
      #pragma unroll
      for (int r = 0; r < 4; ++r) { mrun[r] = -__builtin_inff(); lrun[r] = 0.f; }
    } else {
      #pragma unroll
      for (int g = 0; g < 2; ++g)
        #pragma unroll
        for (int t = 0; t < 8; ++t)
          #pragma unroll
          for (int r = 0; r < 4; ++r) acc[g][t][r] = 0.f;
      stageK((asc ? 0 : qt) * 32);
    }
    __syncthreads();  // prologue TOP: K(first tile) staged & drained

    for (int s = 0; s <= NT; ++s) {
      if (s > 0) __syncthreads();  // TOP: drains stageK(seq s)
      const int jts = asc ? s : (qt - s);            // A tile (valid s<NT)
      const int jtp = asc ? (s - 1) : (qt - s + 1);  // B tile (valid s>=1)
      if (isA) {
        if (s < NT) {
          // --- QK^T: 16 rows x 16 keys, Q streamed from L2 (windowed) ---
          f32x4 sqk;
          #pragma unroll
          for (int r = 0; r < 4; ++r) sqk[r] = 0.f;
          const int key = keyg * 16 + l16;
          #pragma unroll 4
          for (int kk = 0; kk < 16; ++kk) {
            bf16x8 qfr = ld8(qp + kk * 32);
            bf16x8 kfr = ld8(&sK[key * 512 + (((kk * 4 + quad + key) & 63) * 8)]);
            sqk = MFMA16(qfr, kfr, sqk, 0, 0, 0);
          }
          #pragma unroll
          for (int r = 0; r < 4; ++r)
            sS[(rowg * 16 + quad * 4 + r) * 36 + keyg * 16 + l16] = sqk[r];
        } else if (wave < 2) {
          // final slot: row sums -> sL
          #pragma unroll
          for (int r = 0; r < 4; ++r) {
            float l = lrun[r];
            l += __shfl_xor(l, 1);
            l += __shfl_xor(l, 2);
            l += __shfl_xor(l, 4);
            l += __shfl_xor(l, 8);
            if (l16 == 0) sL[wave * 16 + quad * 4 + r] = l;
          }
        }
      } else {
        if (s >= 1) {
          const int pp = (s - 1) & 1;
          const int j0p = jtp * 32;
          // --- rescale acc, then PV(tile jtp): P from sP, V direct from L2 ---
          float alr[2][4];
          #pragma unroll
          for (int g = 0; g < 2; ++g)
            #pragma unroll
            for (int r = 0; r < 4; ++r) alr[g][r] = sAl[pp][g * 16 + quad * 4 + r];
          #pragma unroll
          for (int g = 0; g < 2; ++g)
            #pragma unroll
            for (int t = 0; t < 8; ++t) {
              acc[g][t][0] *= alr[g][0]; acc[g][t][1] *= alr[g][1];
              acc[g][t][2] *= alr[g][2]; acc[g][t][3] *= alr[g][3];
            }
          bf16x8 pf[2];
          #pragma unroll
          for (int g = 0; g < 2; ++g)
            pf[g] = ld8(&sP[pp][(g * 16 + l16) * 40 + quad * 8]);
          #pragma unroll
          for (int t = 0; t < 8; ++t) {
            bf16x8 v = ld8(vrow + (size_t)(t * 16) * Nctx + j0p + quad * 8);
            #pragma unroll
            for (int g = 0; g < 2; ++g)
              acc[g][t] = MFMA16(pf[g], v, acc[g][t], 0, 0, 0);
          }
        }
      }
      // MID: raw barrier, lgkm drain only (stageK DMA stays in flight)
      asm volatile("s_waitcnt lgkmcnt(0)" ::: "memory");
      __builtin_amdgcn_s_barrier();
      __builtin_amdgcn_sched_barrier(0);
      if (isA) {
        if (s < NT && wave < 2) {
          // --- full-row online softmax (waves 0-1: 16 rows x 32 keys each) ---
          const bool diag = (jts == qt);
          const int j0 = jts * 32;
          const int pg = s & 1;
          #pragma unroll
          for (int r = 0; r < 4; ++r) {
            const int lrow = wave * 16 + quad * 4 + r;
            const int qrow = q0 + lrow;
            float sv[2];
            #pragma unroll
            for (int kg = 0; kg < 2; ++kg) {
              int keyj = j0 + kg * 16 + l16;
              float x = sS[lrow * 36 + kg * 16 + l16];
              sv[kg] = (diag && keyj > qrow) ? -__builtin_inff() : x;
            }
            float mx = fmaxf(sv[0], sv[1]);
            mx = fmaxf(mx, __shfl_xor(mx, 1));
            mx = fmaxf(mx, __shfl_xor(mx, 2));
            mx = fmaxf(mx, __shfl_xor(mx, 4));
            mx = fmaxf(mx, __shfl_xor(mx, 8));
            float mnew = fmaxf(mrun[r], mx);
            float a = __expf(mrun[r] - mnew);
            float rs = 0.f;
            #pragma unroll
            for (int kg = 0; kg < 2; ++kg) {
              float pe = __expf(sv[kg] - mnew);
              sP[pg][lrow * 40 + kg * 16 + l16] = f2b(pe);
              rs += pe;
            }
            lrun[r] = lrun[r] * a + rs;
            mrun[r] = mnew;
            if (l16 == 0) sAl[pg][lrow] = a;
          }
        }
      } else {
        if (s + 1 < NT) stageK((asc ? (s + 1) : (qt - s - 1)) * 32);  // for slot s+1
      }
    }
    __syncthreads();  // sL + last sP consumption ordered
    // epilogue: B normalizes and writes its dh-slice
    if (!isA) {
      #pragma unroll
      for (int g = 0; g < 2; ++g) {
        float inv[4];
        #pragma unroll
        for (int r = 0; r < 4; ++r) inv[r] = 1.f / sL[g * 16 + quad * 4 + r];
        #pragma unroll
        for (int t = 0; t < 8; ++t)
          #pragma unroll
          for (int r = 0; r < 4; ++r)
            Yp[((size_t)bh * Nctx + q0 + g * 16 + quad * 4 + r) * Dh + wd + t * 16 + l16] =
                f2b(acc[g][t][r] * inv[r]);
      }
    }
    if (phase == 0) __syncthreads();  // clean phase boundary
  }
}

// ---------------- head-sum + QuickGELU -> bf16 ----------------
__global__ void sumheads_k(const u16* __restrict__ Yp, u16* __restrict__ Ys) {
  size_t idx = (size_t)blockIdx.x * 256 + threadIdx.x;
  size_t e0 = idx * 8;
  int b = (int)(e0 >> 20);
  size_t rem = e0 & ((1u << 20) - 1);
  float s[8];
  #pragma unroll
  for (int e = 0; e < 8; ++e) s[e] = 0.f;
  #pragma unroll
  for (int h = 0; h < Hh; ++h) {
    u16x8 v = *(const u16x8*)&Yp[((size_t)(b * Hh + h) << 20) + rem];
    #pragma unroll
    for (int e = 0; e < 8; ++e) s[e] += b2f(v[e]);
  }
  u16x8 o;
  #pragma unroll
  for (int e = 0; e < 8; ++e) {
    float g = s[e] / (1.f + __expf(-1.702f * s[e]));
    o[e] = f2b(g);
  }
  *(u16x8*)&Ys[e0] = o;
}

extern "C" void kernel_launch(void* const* d_in, const int* in_sizes, int n_in,
                              void* d_out, int out_size, void* d_ws, size_t ws_size,
                              hipStream_t stream) {
  const float* x  = (const float*)d_in[0];
  const float* cs = (const float*)d_in[1];
  const float* sn = (const float*)d_in[2];
  int wbase = 4;                        // target_mask (bool tril) at idx 3, hard-coded
  if (n_in == 9) wbase = 3;
  if (wbase + 3 < n_in && in_sizes[wbase + 3] != 4096) wbase = (wbase == 4) ? 3 : 4;
  const float* Wq = (const float*)d_in[wbase + 0];
  const float* Wk = (const float*)d_in[wbase + 1];
  const float* Wv = (const float*)d_in[wbase + 2];
  const float* bv = (const float*)d_in[wbase + 3];
  const float* Wo = (const float*)d_in[wbase + 4];
  const float* bo = (const float*)d_in[wbase + 5];

  // ws layout (132.5 MiB), with aliasing:
  //  [0,32M): WqT@0, WkT@4M, WvT@8M, xb@12M  -> later reused as Vt
  //  [32,64M): Qb   [64,96M): Kb   [96,128M): Vb -> later reused as Yp
  //  [128M,+0.5M): WoT   [+0.5M,+4.5M): Ys
  char* ws = (char*)d_ws;
  const size_t MiB = 1ull << 20;
  u16* WqT = (u16*)(ws + 0 * MiB);
  u16* WkT = (u16*)(ws + 4 * MiB);
  u16* WvT = (u16*)(ws + 8 * MiB);
  u16* xb  = (u16*)(ws + 12 * MiB);
  u16* Vt  = (u16*)(ws + 0 * MiB);    // alias: weights/xb dead after QKV gemms
  u16* Qb  = (u16*)(ws + 32 * MiB);
  u16* Kb  = (u16*)(ws + 64 * MiB);
  u16* Vb  = (u16*)(ws + 96 * MiB);
  u16* Yp  = Vb;                      // alias: Vb dead after vtrans
  u16* WoT = (u16*)(ws + 128 * MiB);
  u16* Ys  = (u16*)(ws + 128 * MiB + 512 * 1024);

  dim3 tb(32, 8);
  transpose_k<<<dim3(Ff / 32, Dm / 32), tb, 0, stream>>>(Wq, WqT, Dm, Ff);
  transpose_k<<<dim3(Ff / 32, Dm / 32), tb, 0, stream>>>(Wk, WkT, Dm, Ff);
  transpose_k<<<dim3(Ff / 32, Dm / 32), tb, 0, stream>>>(Wv, WvT, Dm, Ff);
  transpose_k<<<dim3(Dm / 32, Dm / 32), tb, 0, stream>>>(Wo, WoT, Dm, Dm);
  convert_k<<<dim3(Mrows * Dm / 8 / 256), 256, 0, stream>>>(x, xb, Mrows * Dm / 8);

  gemm2_k<1><<<dim3(Ff / 128, Mrows / 128), 256, 0, stream>>>(xb, WqT, Qb, nullptr, cs, sn, Ff, Dm);
  gemm2_k<1><<<dim3(Ff / 128, Mrows / 128), 256, 0, stream>>>(xb, WkT, Kb, nullptr, cs, sn, Ff, Dm);
  gemm2_k<2><<<dim3(Ff / 128, Mrows / 128), 256, 0, stream>>>(xb, WvT, Vb, bv, nullptr, nullptr, Ff, Dm);

  vtrans_k<<<dim3(Nctx / 64, Dh / 64, Bb * Hh), 256, 0, stream>>>(Vb, Vt);

  attn_k<<<dim3(512), 512, 0, stream>>>(Qb, Kb, Vt, Yp);

  sumheads_k<<<dim3(Mrows * Dm / 8 / 256), 256, 0, stream>>>(Yp, Ys);

  gemm2_k<3><<<dim3(Dm / 128, Mrows / 128), 256, 0, stream>>>(Ys, WoT, d_out, bo, nullptr, nullptr, Dm, Dm);
}